// Round 1
// baseline (221.332 us; speedup 1.0000x reference)
//
#include <hip/hip_runtime.h>

#define NN 1536      // n_nodes
#define FDIM 32      // p == fts == 32

// ---------------------------------------------------------------------------
// Prep: Q_l = P @ W1[l] for l = 1,2.  Store QIp[i][l*32+f] = Q + b1,
// RJn[j][l*32+f] = -Q so that h = relu(QIp[i] + RJn[j]).
// ---------------------------------------------------------------------------
__global__ __launch_bounds__(256) void gud_prep(const float* __restrict__ P,
                                                const float* __restrict__ W1,
                                                const float* __restrict__ b1,
                                                float* __restrict__ QIp,
                                                float* __restrict__ RJn) {
    int gid = blockIdx.x * 256 + threadIdx.x;   // 0 .. NN*64-1
    int i  = gid >> 6;
    int lf = gid & 63;
    int l  = (lf >> 5) + 1;   // 1 or 2
    int f  = lf & 31;
    const float* prow = P + i * FDIM;
    const float* w    = W1 + l * FDIM * FDIM + f;
    float q = 0.f;
#pragma unroll
    for (int c = 0; c < FDIM; ++c) q = fmaf(prow[c], w[c * FDIM], q);
    QIp[i * 64 + lf] = q + b1[l * FDIM + f];
    RJn[i * 64 + lf] = -q;
}

// ---------------------------------------------------------------------------
// f32 SGEMM: A2 = A * A  (NN x NN, row-major). BM=BN=64, BK=16, 128 threads,
// 8x4 per thread. Transposed A-tile in LDS for float4 reads.
// ---------------------------------------------------------------------------
#define BM 64
#define BN 64
#define BK 16

__global__ __launch_bounds__(128) void gud_sgemm(const float* __restrict__ A,
                                                 float* __restrict__ C) {
    __shared__ alignas(16) float Ast[BK][BM + 4];  // [k][m]
    __shared__ alignas(16) float Bs[BK][BN + 4];   // [k][n]

    const int tid = threadIdx.x;
    const int tx  = tid & 15;   // n dim: 16 * 4 = 64
    const int ty  = tid >> 4;   // m dim: 8 * 8 = 64
    const int i0  = blockIdx.y * BM;
    const int j0  = blockIdx.x * BN;

    float acc[8][4] = {};

    for (int k0 = 0; k0 < NN; k0 += BK) {
        // A tile: 64 rows x 16 k = 256 float4, 2 per thread (transpose into LDS)
#pragma unroll
        for (int ph = 0; ph < 2; ++ph) {
            int idx = ph * 128 + tid;            // 0..255
            int r   = idx >> 2;                  // 0..63
            int c4  = (idx & 3) * 4;             // 0,4,8,12
            float4 v = *reinterpret_cast<const float4*>(
                &A[(size_t)(i0 + r) * NN + k0 + c4]);
            Ast[c4 + 0][r] = v.x;
            Ast[c4 + 1][r] = v.y;
            Ast[c4 + 2][r] = v.z;
            Ast[c4 + 3][r] = v.w;
        }
        // B tile: 16 k-rows x 64 cols = 256 float4, 2 per thread
#pragma unroll
        for (int ph = 0; ph < 2; ++ph) {
            int idx = ph * 128 + tid;
            int r   = idx >> 4;                  // 0..15
            int c4  = (idx & 15) * 4;            // 0..60
            float4 v = *reinterpret_cast<const float4*>(
                &A[(size_t)(k0 + r) * NN + j0 + c4]);
            *reinterpret_cast<float4*>(&Bs[r][c4]) = v;
        }
        __syncthreads();

#pragma unroll
        for (int kk = 0; kk < BK; ++kk) {
            float4 a0 = *reinterpret_cast<const float4*>(&Ast[kk][ty * 8]);
            float4 a1 = *reinterpret_cast<const float4*>(&Ast[kk][ty * 8 + 4]);
            float4 b  = *reinterpret_cast<const float4*>(&Bs[kk][tx * 4]);
            float am[8] = {a0.x, a0.y, a0.z, a0.w, a1.x, a1.y, a1.z, a1.w};
            float bn[4] = {b.x, b.y, b.z, b.w};
#pragma unroll
            for (int m = 0; m < 8; ++m)
#pragma unroll
                for (int n = 0; n < 4; ++n)
                    acc[m][n] = fmaf(am[m], bn[n], acc[m][n]);
        }
        __syncthreads();
    }

#pragma unroll
    for (int m = 0; m < 8; ++m) {
        float4 v = {acc[m][0], acc[m][1], acc[m][2], acc[m][3]};
        *reinterpret_cast<float4*>(
            &C[(size_t)(i0 + ty * 8 + m) * NN + j0 + tx * 4]) = v;
    }
}

// ---------------------------------------------------------------------------
// Fused conv: conv[i,j] = A[i,j]*m1(i,j) + A2[i,j]*m2(i,j) + (i==j)*c0
// m_l(i,j) = sum_f relu(QIp[i,f] + RJn[j,f]) * W2[l,f] + b2[l]
// Block: 256 lanes = 256 consecutive j; 16 rows i per block.
// RJ for this lane's j lives in registers; QI rows broadcast from LDS.
// ---------------------------------------------------------------------------
__global__ __launch_bounds__(256) void gud_conv(const float* __restrict__ A,
                                                const float* __restrict__ A2,
                                                const float* __restrict__ QIp,
                                                const float* __restrict__ RJn,
                                                const float* __restrict__ b1,
                                                const float* __restrict__ W2,
                                                const float* __restrict__ b2,
                                                float* __restrict__ out) {
    __shared__ alignas(16) float Qis[16][64];

    const int tid = threadIdx.x;
    const int j   = blockIdx.x * 256 + tid;
    const int i0  = blockIdx.y * 16;

    // stage QI tile: 16 rows x 64 floats = 256 float4, 1 per thread
    {
        int r  = tid >> 4;
        int q4 = (tid & 15) * 4;
        *reinterpret_cast<float4*>(&Qis[r][q4]) =
            *reinterpret_cast<const float4*>(&QIp[(size_t)(i0 + r) * 64 + q4]);
    }

    // this lane's RJ row in registers
    float rj[64];
#pragma unroll
    for (int q4 = 0; q4 < 64; q4 += 4) {
        float4 v = *reinterpret_cast<const float4*>(&RJn[(size_t)j * 64 + q4]);
        rj[q4] = v.x; rj[q4 + 1] = v.y; rj[q4 + 2] = v.z; rj[q4 + 3] = v.w;
    }

    // c0 = MLP_0(0) = sum_f relu(b1[0,f])*W2[0,f] + b2[0]  (uniform)
    float c0 = b2[0];
#pragma unroll
    for (int f = 0; f < FDIM; ++f) c0 = fmaf(fmaxf(b1[f], 0.f), W2[f], c0);
    const float bb1 = b2[1];
    const float bb2 = b2[2];

    __syncthreads();

    for (int ii = 0; ii < 16; ++ii) {
        const int i = i0 + ii;
        // pull the QI row into registers via wide broadcast reads
        float4 q4v[16];
#pragma unroll
        for (int t = 0; t < 16; ++t)
            q4v[t] = *reinterpret_cast<const float4*>(&Qis[ii][t * 4]);
        const float* qf = reinterpret_cast<const float*>(q4v);

        float m1 = 0.f, m2 = 0.f;
#pragma unroll
        for (int f = 0; f < FDIM; ++f) {
            float t = fmaxf(qf[f] + rj[f], 0.f);
            m1 = fmaf(t, W2[32 + f], m1);
        }
#pragma unroll
        for (int f = 0; f < FDIM; ++f) {
            float t = fmaxf(qf[32 + f] + rj[32 + f], 0.f);
            m2 = fmaf(t, W2[64 + f], m2);
        }

        const size_t off = (size_t)i * NN + j;
        float r = A[off] * (m1 + bb1) + A2[off] * (m2 + bb2);
        if (i == j) r += c0;
        out[off] = r;
    }
}

// ---------------------------------------------------------------------------
extern "C" void kernel_launch(void* const* d_in, const int* in_sizes, int n_in,
                              void* d_out, int out_size, void* d_ws, size_t ws_size,
                              hipStream_t stream) {
    const float* A  = (const float*)d_in[0];   // [NN,NN] A_norm
    const float* P  = (const float*)d_in[1];   // [NN,32]
    const float* W1 = (const float*)d_in[2];   // [3,32,32]
    const float* b1 = (const float*)d_in[3];   // [3,32]
    const float* W2 = (const float*)d_in[4];   // [3,32,1]
    const float* b2 = (const float*)d_in[5];   // [3,1]
    float* out = (float*)d_out;

    float* A2  = (float*)d_ws;                         // NN*NN floats
    float* QIp = A2 + (size_t)NN * NN;                 // NN*64
    float* RJn = QIp + (size_t)NN * 64;                // NN*64

    gud_prep<<<dim3(NN * 64 / 256), 256, 0, stream>>>(P, W1, b1, QIp, RJn);
    gud_sgemm<<<dim3(NN / BN, NN / BM), 128, 0, stream>>>(A, A2);
    gud_conv<<<dim3(NN / 256, NN / 16), 256, 0, stream>>>(A, A2, QIp, RJn,
                                                          b1, W2, b2, out);
}

// Round 2
// 88.302 us; speedup vs baseline: 2.5065x; 2.5065x over previous
//
#include <hip/hip_runtime.h>

#define NN 1536      // n_nodes
#define FDIM 32      // p == fts == 32
#define TG 96        // GEMM tile (96*16 = 1536, grid 16x16 = 256 blocks = 1/CU)
#define KS 32        // K-step (one mfma_16x16x32 worth of K)

typedef __attribute__((ext_vector_type(8))) __bf16 bf16x8;
typedef __attribute__((ext_vector_type(4))) float f32x4;

typedef __attribute__((address_space(3))) unsigned char as3_u8;
typedef __attribute__((address_space(1))) unsigned char as1_u8;

__device__ __forceinline__ void gload_lds16(const void* g, void* l) {
    __builtin_amdgcn_global_load_lds((const as1_u8*)g, (as3_u8*)l, 16, 0, 0);
}

// ---------------------------------------------------------------------------
// Split A into bf16 hi/lo: Ah = rne_bf16(a), Al = rne_bf16(a - float(Ah)).
// ---------------------------------------------------------------------------
__device__ __forceinline__ unsigned short bf16rne(float f) {
    unsigned u = __float_as_uint(f);
    return (unsigned short)((u + 0x7FFFu + ((u >> 16) & 1u)) >> 16);
}

__global__ __launch_bounds__(256) void gud_split(const float* __restrict__ A,
                                                 unsigned short* __restrict__ Ah,
                                                 unsigned short* __restrict__ Al) {
    int gid = blockIdx.x * 256 + threadIdx.x;      // 4 floats per thread
    float4 v = reinterpret_cast<const float4*>(A)[gid];
    ushort4 h, l;
    float x;
    x = v.x; h.x = bf16rne(x); l.x = bf16rne(x - __uint_as_float((unsigned)h.x << 16));
    x = v.y; h.y = bf16rne(x); l.y = bf16rne(x - __uint_as_float((unsigned)h.y << 16));
    x = v.z; h.z = bf16rne(x); l.z = bf16rne(x - __uint_as_float((unsigned)h.z << 16));
    x = v.w; h.w = bf16rne(x); l.w = bf16rne(x - __uint_as_float((unsigned)h.w << 16));
    reinterpret_cast<ushort4*>(Ah)[gid] = h;
    reinterpret_cast<ushort4*>(Al)[gid] = l;
}

// ---------------------------------------------------------------------------
// Prep: Q_l = P @ W1[l] for l = 1,2.  QIp[i][l*32+f] = Q + b1, RJn[j] = -Q.
// ---------------------------------------------------------------------------
__global__ __launch_bounds__(256) void gud_prep(const float* __restrict__ P,
                                                const float* __restrict__ W1,
                                                const float* __restrict__ b1,
                                                float* __restrict__ QIp,
                                                float* __restrict__ RJn) {
    int gid = blockIdx.x * 256 + threadIdx.x;   // 0 .. NN*64-1
    int i  = gid >> 6;
    int lf = gid & 63;
    int l  = (lf >> 5) + 1;   // 1 or 2
    int f  = lf & 31;
    const float* prow = P + i * FDIM;
    const float* w    = W1 + l * FDIM * FDIM + f;
    float q = 0.f;
#pragma unroll
    for (int c = 0; c < FDIM; ++c) q = fmaf(prow[c], w[c * FDIM], q);
    QIp[i * 64 + lf] = q + b1[l * FDIM + f];
    RJn[i * 64 + lf] = -q;
}

// ---------------------------------------------------------------------------
// MFMA GEMM: C = A*A (f32 out) via bf16 hi/lo split. A symmetric, so the
// B-operand tile (col-major [col][k]) is just rows j0.. of Ah/Al.
// LDS tiles [96 rows][4 k-slots of 16B], slot XOR-swizzled by (row>>1)&3;
// the inverse swizzle is applied to the per-lane GLOBAL source address so
// the global_load_lds destination stays linear (both-sides-or-neither).
// ---------------------------------------------------------------------------
__global__ __launch_bounds__(256) void gud_gemm(const unsigned short* __restrict__ Ah,
                                                const unsigned short* __restrict__ Al,
                                                float* __restrict__ C) {
    // 2 buffers x 4 tiles(Ah,Al,Bh,Bl) x 96 rows x 64B = 49152 B
    __shared__ char smem[2 * 4 * 96 * 64];

    const int tid  = threadIdx.x;
    const int lane = tid & 63;
    const int w    = tid >> 6;          // wave 0..3
    const int wr   = w >> 1, wc = w & 1;
    const int i0   = blockIdx.y * TG;
    const int j0   = blockIdx.x * TG;

    // ---- staging setup: wave w owns tile w (0=Ah,1=Al rows i0; 2=Ah,3=Al rows j0)
    const unsigned short* src = (w & 1) ? Al : Ah;
    const int rowbase = (w < 2) ? i0 : j0;
    int goffs[6];                        // per-lane global byte offsets (k0=0)
#pragma unroll
    for (int s = 0; s < 6; ++s) {
        int rt    = 16 * s + (lane >> 2);          // row within tile 0..95
        int chunk = (lane & 3) ^ ((rt >> 1) & 3);  // inverse swizzle on source
        goffs[s]  = (rowbase + rt) * (NN * 2) + chunk * 16;
    }
    char* ltile0 = smem + w * 6144;
    char* ltile1 = smem + 24576 + w * 6144;

    // ---- fragment read offsets (swizzled)
    int aoff[3], boff[3];
    const int kb = lane >> 4;            // k-chunk 0..3
#pragma unroll
    for (int m = 0; m < 3; ++m) {
        int ra  = wr * 48 + m * 16 + (lane & 15);
        aoff[m] = ra * 64 + ((kb ^ ((ra >> 1) & 3)) * 16);
        int rb  = wc * 48 + m * 16 + (lane & 15);
        boff[m] = rb * 64 + ((kb ^ ((rb >> 1) & 3)) * 16);
    }

    f32x4 acc[3][3];
#pragma unroll
    for (int m = 0; m < 3; ++m)
#pragma unroll
        for (int n = 0; n < 3; ++n) acc[m][n] = (f32x4){0.f, 0.f, 0.f, 0.f};

    // ---- prologue: stage k-tile 0 into buffer 0
#pragma unroll
    for (int s = 0; s < 6; ++s)
        gload_lds16((const char*)src + goffs[s], ltile0 + s * 1024);
    __syncthreads();

    for (int kt = 0; kt < NN / KS; ++kt) {
        const int cur = kt & 1;
        if (kt + 1 < NN / KS) {
            const int kbyte = (kt + 1) * (KS * 2);
            char* dst = cur ? ltile0 : ltile1;
#pragma unroll
            for (int s = 0; s < 6; ++s)
                gload_lds16((const char*)src + goffs[s] + kbyte, dst + s * 1024);
        }
        const char* buf = smem + cur * 24576;

        bf16x8 ah[3], al[3], bh[3], bl[3];
#pragma unroll
        for (int m = 0; m < 3; ++m) {
            ah[m] = *(const bf16x8*)(buf + 0 * 6144 + aoff[m]);
            al[m] = *(const bf16x8*)(buf + 1 * 6144 + aoff[m]);
            bh[m] = *(const bf16x8*)(buf + 2 * 6144 + boff[m]);
            bl[m] = *(const bf16x8*)(buf + 3 * 6144 + boff[m]);
        }
#pragma unroll
        for (int m = 0; m < 3; ++m)
#pragma unroll
            for (int n = 0; n < 3; ++n) {
                acc[m][n] = __builtin_amdgcn_mfma_f32_16x16x32_bf16(ah[m], bh[n], acc[m][n], 0, 0, 0);
                acc[m][n] = __builtin_amdgcn_mfma_f32_16x16x32_bf16(al[m], bh[n], acc[m][n], 0, 0, 0);
                acc[m][n] = __builtin_amdgcn_mfma_f32_16x16x32_bf16(ah[m], bl[n], acc[m][n], 0, 0, 0);
            }
        __syncthreads();
    }

    // ---- epilogue: C/D layout col = lane&15, row = (lane>>4)*4 + reg
    const int crow = (lane >> 4) * 4;
    const int ccol = lane & 15;
#pragma unroll
    for (int m = 0; m < 3; ++m)
#pragma unroll
        for (int n = 0; n < 3; ++n) {
            const int ib = i0 + wr * 48 + m * 16 + crow;
            const int jb = j0 + wc * 48 + n * 16 + ccol;
#pragma unroll
            for (int r = 0; r < 4; ++r)
                C[(size_t)(ib + r) * NN + jb] = acc[m][n][r];
        }
}

// ---------------------------------------------------------------------------
// Fused conv, IN PLACE on io (= A2 on input, conv on output — elementwise):
// io[i,j] = A[i,j]*m1(i,j) + io[i,j]*m2(i,j) + (i==j)*c0
// ---------------------------------------------------------------------------
__global__ __launch_bounds__(256) void gud_conv(const float* __restrict__ A,
                                                float* io,
                                                const float* __restrict__ QIp,
                                                const float* __restrict__ RJn,
                                                const float* __restrict__ b1,
                                                const float* __restrict__ W2,
                                                const float* __restrict__ b2) {
    __shared__ alignas(16) float Qis[16][64];

    const int tid = threadIdx.x;
    const int j   = blockIdx.x * 256 + tid;
    const int i0  = blockIdx.y * 16;

    {
        int r  = tid >> 4;
        int q4 = (tid & 15) * 4;
        *reinterpret_cast<float4*>(&Qis[r][q4]) =
            *reinterpret_cast<const float4*>(&QIp[(size_t)(i0 + r) * 64 + q4]);
    }

    float rj[64];
#pragma unroll
    for (int q4 = 0; q4 < 64; q4 += 4) {
        float4 v = *reinterpret_cast<const float4*>(&RJn[(size_t)j * 64 + q4]);
        rj[q4] = v.x; rj[q4 + 1] = v.y; rj[q4 + 2] = v.z; rj[q4 + 3] = v.w;
    }

    float c0 = b2[0];
#pragma unroll
    for (int f = 0; f < FDIM; ++f) c0 = fmaf(fmaxf(b1[f], 0.f), W2[f], c0);
    const float bb1 = b2[1];
    const float bb2 = b2[2];

    __syncthreads();

    for (int ii = 0; ii < 16; ++ii) {
        const int i = i0 + ii;
        float4 q4v[16];
#pragma unroll
        for (int t = 0; t < 16; ++t)
            q4v[t] = *reinterpret_cast<const float4*>(&Qis[ii][t * 4]);
        const float* qf = reinterpret_cast<const float*>(q4v);

        float m1 = 0.f, m2 = 0.f;
#pragma unroll
        for (int f = 0; f < FDIM; ++f) {
            float t = fmaxf(qf[f] + rj[f], 0.f);
            m1 = fmaf(t, W2[32 + f], m1);
        }
#pragma unroll
        for (int f = 0; f < FDIM; ++f) {
            float t = fmaxf(qf[32 + f] + rj[32 + f], 0.f);
            m2 = fmaf(t, W2[64 + f], m2);
        }

        const size_t off = (size_t)i * NN + j;
        float r = A[off] * (m1 + bb1) + io[off] * (m2 + bb2);
        if (i == j) r += c0;
        io[off] = r;
    }
}

// ---------------------------------------------------------------------------
extern "C" void kernel_launch(void* const* d_in, const int* in_sizes, int n_in,
                              void* d_out, int out_size, void* d_ws, size_t ws_size,
                              hipStream_t stream) {
    const float* A  = (const float*)d_in[0];   // [NN,NN] A_norm (symmetric)
    const float* P  = (const float*)d_in[1];   // [NN,32]
    const float* W1 = (const float*)d_in[2];   // [3,32,32]
    const float* b1 = (const float*)d_in[3];   // [3,32]
    const float* W2 = (const float*)d_in[4];   // [3,32,1]
    const float* b2 = (const float*)d_in[5];   // [3,1]
    float* out = (float*)d_out;

    unsigned short* Ahh = (unsigned short*)d_ws;                 // NN*NN bf16
    unsigned short* All = Ahh + (size_t)NN * NN;                 // NN*NN bf16
    float* QIp = (float*)(All + (size_t)NN * NN);                // NN*64 f32
    float* RJn = QIp + (size_t)NN * 64;                          // NN*64 f32

    gud_split<<<dim3(NN * NN / 1024), 256, 0, stream>>>(A, Ahh, All);
    gud_prep<<<dim3(NN * 64 / 256), 256, 0, stream>>>(P, W1, b1, QIp, RJn);
    gud_gemm<<<dim3(NN / TG, NN / TG), 256, 0, stream>>>(Ahh, All, out);
    gud_conv<<<dim3(NN / 256, NN / 16), 256, 0, stream>>>(A, out, QIp, RJn,
                                                          b1, W2, b2);
}

// Round 3
// 55.878 us; speedup vs baseline: 3.9610x; 1.5803x over previous
//
#include <hip/hip_runtime.h>

#define NN 1536      // n_nodes
#define FDIM 32      // p == fts == 32
#define TG 96        // GEMM tile (grid 16x16 = 256 blocks = 1/CU)
#define KS 32        // K-step
#define NT (NN / KS) // 48 K-tiles

typedef __attribute__((ext_vector_type(8))) __bf16 bf16x8;
typedef __attribute__((ext_vector_type(4))) float f32x4;

typedef __attribute__((address_space(3))) unsigned char as3_u8;
typedef __attribute__((address_space(1))) unsigned char as1_u8;

__device__ __forceinline__ void gload_lds16(const void* g, void* l) {
    __builtin_amdgcn_global_load_lds((const as1_u8*)g, (as3_u8*)l, 16, 0, 0);
}

// ---------------------------------------------------------------------------
// Split A into bf16 hi/lo: Ah = rne_bf16(a), Al = rne_bf16(a - float(Ah)).
// ---------------------------------------------------------------------------
__device__ __forceinline__ unsigned short bf16rne(float f) {
    unsigned u = __float_as_uint(f);
    return (unsigned short)((u + 0x7FFFu + ((u >> 16) & 1u)) >> 16);
}

__global__ __launch_bounds__(256) void gud_split(const float* __restrict__ A,
                                                 unsigned short* __restrict__ Ah,
                                                 unsigned short* __restrict__ Al) {
    int gid = blockIdx.x * 256 + threadIdx.x;      // 4 floats per thread
    float4 v = reinterpret_cast<const float4*>(A)[gid];
    ushort4 h, l;
    float x;
    x = v.x; h.x = bf16rne(x); l.x = bf16rne(x - __uint_as_float((unsigned)h.x << 16));
    x = v.y; h.y = bf16rne(x); l.y = bf16rne(x - __uint_as_float((unsigned)h.y << 16));
    x = v.z; h.z = bf16rne(x); l.z = bf16rne(x - __uint_as_float((unsigned)h.z << 16));
    x = v.w; h.w = bf16rne(x); l.w = bf16rne(x - __uint_as_float((unsigned)h.w << 16));
    reinterpret_cast<ushort4*>(Ah)[gid] = h;
    reinterpret_cast<ushort4*>(Al)[gid] = l;
}

// ---------------------------------------------------------------------------
// Prep: Q_l = P @ W1[l] for l = 1,2.  QIp[i][l*32+f] = Q + b1, RJn[j] = -Q.
// ---------------------------------------------------------------------------
__global__ __launch_bounds__(256) void gud_prep(const float* __restrict__ P,
                                                const float* __restrict__ W1,
                                                const float* __restrict__ b1,
                                                float* __restrict__ QIp,
                                                float* __restrict__ RJn) {
    int gid = blockIdx.x * 256 + threadIdx.x;   // 0 .. NN*64-1
    int i  = gid >> 6;
    int lf = gid & 63;
    int l  = (lf >> 5) + 1;   // 1 or 2
    int f  = lf & 31;
    const float* prow = P + i * FDIM;
    const float* w    = W1 + l * FDIM * FDIM + f;
    float q = 0.f;
#pragma unroll
    for (int c = 0; c < FDIM; ++c) q = fmaf(prow[c], w[c * FDIM], q);
    QIp[i * 64 + lf] = q + b1[l * FDIM + f];
    RJn[i * 64 + lf] = -q;
}

// ---------------------------------------------------------------------------
// Fused MFMA GEMM + conv epilogue.
//   acc = A*A (bf16 hi/lo split, 3 MFMA products), then
//   out[i,j] = A[i,j]*(m1+bb1) + acc[i,j]*(m2+bb2) + (i==j)*c0
// Pipeline: 3 LDS buffers, 2-deep prefetch, counted vmcnt(6) + raw s_barrier.
// QI/RJ staged (transposed [chunk][row] f32 layout) at kernel start.
// ---------------------------------------------------------------------------
__global__ __launch_bounds__(256, 1) void gud_gemm(
        const unsigned short* __restrict__ Ah,
        const unsigned short* __restrict__ Al,
        const float* __restrict__ A,
        const float* __restrict__ QIp,
        const float* __restrict__ RJn,
        const float* __restrict__ b1,
        const float* __restrict__ W2,
        const float* __restrict__ b2,
        float* __restrict__ out) {
    // 3 gemm bufs (each 4 subtiles x 96 rows x 64B = 24576) + QI + RJ (24576 ea)
    __shared__ char smem[5 * 24576];

    const int tid  = threadIdx.x;
    const int lane = tid & 63;
    const int w    = tid >> 6;          // wave 0..3
    const int wr   = w >> 1, wc = w & 1;
    const int i0   = blockIdx.y * TG;
    const int j0   = blockIdx.x * TG;

    char* QIl = smem + 3 * 24576;
    char* RJl = QIl + 24576;

    // ---- stage QI/RJ first (oldest in vmcnt FIFO). Transposed layout:
    // LDS float4 slot (c*96 + row) = QIp[i0+row][c*4 .. c*4+3].
#pragma unroll
    for (int sl = 0; sl < 6; ++sl) {
        int base = (w * 6 + sl) * 64;       // wave-uniform
        int idx  = base + lane;
        int c    = idx / 96;
        int row  = idx - c * 96;
        gload_lds16(QIp + (size_t)(i0 + row) * 64 + c * 4, QIl + base * 16);
    }
#pragma unroll
    for (int sl = 0; sl < 6; ++sl) {
        int base = (w * 6 + sl) * 64;
        int idx  = base + lane;
        int c    = idx / 96;
        int row  = idx - c * 96;
        gload_lds16(RJn + (size_t)(j0 + row) * 64 + c * 4, RJl + base * 16);
    }

    // ---- GEMM staging setup: wave w owns subtile w (0=Ah,1=Al @i0; 2=Ah,3=Al @j0)
    const unsigned short* src = (w & 1) ? Al : Ah;
    const int rowbase = (w < 2) ? i0 : j0;
    int goffs[6];
#pragma unroll
    for (int s = 0; s < 6; ++s) {
        int rt    = 16 * s + (lane >> 2);          // row within tile 0..95
        int chunk = (lane & 3) ^ ((rt >> 1) & 3);  // inverse swizzle on source
        goffs[s]  = (rowbase + rt) * (NN * 2) + chunk * 16;
    }

    // ---- fragment read offsets (swizzled)
    int aoff[3], boff[3];
    const int kb = lane >> 4;
#pragma unroll
    for (int m = 0; m < 3; ++m) {
        int ra  = wr * 48 + m * 16 + (lane & 15);
        aoff[m] = ra * 64 + ((kb ^ ((ra >> 1) & 3)) * 16);
        int rb  = wc * 48 + m * 16 + (lane & 15);
        boff[m] = rb * 64 + ((kb ^ ((rb >> 1) & 3)) * 16);
    }

    f32x4 acc[3][3];
#pragma unroll
    for (int m = 0; m < 3; ++m)
#pragma unroll
        for (int n = 0; n < 3; ++n) acc[m][n] = (f32x4){0.f, 0.f, 0.f, 0.f};

    // ---- prologue: stage k-tiles 0,1 into buffers 0,1
#pragma unroll
    for (int s = 0; s < 6; ++s)
        gload_lds16((const char*)src + goffs[s], smem + w * 6144 + s * 1024);
#pragma unroll
    for (int s = 0; s < 6; ++s)
        gload_lds16((const char*)src + goffs[s] + 64, smem + 24576 + w * 6144 + s * 1024);

    auto compute = [&](const char* buf) {
        bf16x8 ahf[3], alf[3], bhf[3], blf[3];
#pragma unroll
        for (int m = 0; m < 3; ++m) {
            ahf[m] = *(const bf16x8*)(buf + 0 * 6144 + aoff[m]);
            alf[m] = *(const bf16x8*)(buf + 1 * 6144 + aoff[m]);
            bhf[m] = *(const bf16x8*)(buf + 2 * 6144 + boff[m]);
            blf[m] = *(const bf16x8*)(buf + 3 * 6144 + boff[m]);
        }
#pragma unroll
        for (int m = 0; m < 3; ++m)
#pragma unroll
            for (int n = 0; n < 3; ++n) {
                acc[m][n] = __builtin_amdgcn_mfma_f32_16x16x32_bf16(ahf[m], bhf[n], acc[m][n], 0, 0, 0);
                acc[m][n] = __builtin_amdgcn_mfma_f32_16x16x32_bf16(alf[m], bhf[n], acc[m][n], 0, 0, 0);
                acc[m][n] = __builtin_amdgcn_mfma_f32_16x16x32_bf16(ahf[m], blf[n], acc[m][n], 0, 0, 0);
            }
    };

    // ---- main loop: counted vmcnt keeps 2 k-tiles in flight across barriers
    for (int kt = 0; kt < NT - 1; ++kt) {
        asm volatile("s_waitcnt vmcnt(6)" ::: "memory");
        __builtin_amdgcn_s_barrier();
        if (kt + 2 < NT) {   // stage kt+2 AFTER barrier (its buffer is now free)
            char* dst = smem + ((kt + 2) % 3) * 24576 + w * 6144;
            const int kbyte = (kt + 2) * 64;
#pragma unroll
            for (int s = 0; s < 6; ++s)
                gload_lds16((const char*)src + goffs[s] + kbyte, dst + s * 1024);
        }
        compute(smem + (kt % 3) * 24576);
    }
    asm volatile("s_waitcnt vmcnt(0)" ::: "memory");
    __builtin_amdgcn_s_barrier();
    compute(smem + ((NT - 1) % 3) * 24576);

    // ================= fused conv epilogue =================
    const int crow = (lane >> 4) * 4;
    const int ccol = lane & 15;
    int il[3], jl[3];
#pragma unroll
    for (int m = 0; m < 3; ++m) il[m] = wr * 48 + m * 16 + crow;
#pragma unroll
    for (int n = 0; n < 3; ++n) jl[n] = wc * 48 + n * 16 + ccol;

    // A values (issued early; compiler schedules under pass-1 VALU)
    float av[3][3][4];
#pragma unroll
    for (int m = 0; m < 3; ++m)
#pragma unroll
        for (int n = 0; n < 3; ++n)
#pragma unroll
            for (int r = 0; r < 4; ++r)
                av[m][n][r] = A[(size_t)(i0 + il[m] + r) * NN + j0 + jl[n]];

    float c0 = b2[0];
#pragma unroll
    for (int f = 0; f < FDIM; ++f) c0 = fmaf(fmaxf(b1[f], 0.f), W2[f], c0);
    const float bb1 = b2[1], bb2 = b2[2];

    float mm[3][3][4];
    // ---- pass 1: chunks 0..7 (f 0..31, weights W2[1]) -> m1
#pragma unroll
    for (int m = 0; m < 3; ++m)
#pragma unroll
        for (int n = 0; n < 3; ++n)
#pragma unroll
            for (int r = 0; r < 4; ++r) mm[m][n][r] = 0.f;
#pragma unroll
    for (int c = 0; c < 8; ++c) {
        f32x4 rj[3];
#pragma unroll
        for (int n = 0; n < 3; ++n)
            rj[n] = *(const f32x4*)(RJl + (c * 96 + jl[n]) * 16);
        f32x4 qi[3][4];
#pragma unroll
        for (int m = 0; m < 3; ++m)
#pragma unroll
            for (int r = 0; r < 4; ++r)
                qi[m][r] = *(const f32x4*)(QIl + (c * 96 + il[m] + r) * 16);
        f32x4 w2v = *(const f32x4*)(W2 + 32 + c * 4);
#pragma unroll
        for (int m = 0; m < 3; ++m)
#pragma unroll
            for (int n = 0; n < 3; ++n)
#pragma unroll
                for (int r = 0; r < 4; ++r)
#pragma unroll
                    for (int e = 0; e < 4; ++e)
                        mm[m][n][r] = fmaf(fmaxf(qi[m][r][e] + rj[n][e], 0.f),
                                           w2v[e], mm[m][n][r]);
    }
    // combine pass 1 into av: av = A*(m1+bb1)
#pragma unroll
    for (int m = 0; m < 3; ++m)
#pragma unroll
        for (int n = 0; n < 3; ++n)
#pragma unroll
            for (int r = 0; r < 4; ++r)
                av[m][n][r] *= (mm[m][n][r] + bb1);

    // ---- pass 2: chunks 8..15 (f 32..63, weights W2[2]) -> m2
#pragma unroll
    for (int m = 0; m < 3; ++m)
#pragma unroll
        for (int n = 0; n < 3; ++n)
#pragma unroll
            for (int r = 0; r < 4; ++r) mm[m][n][r] = 0.f;
#pragma unroll
    for (int c = 8; c < 16; ++c) {
        f32x4 rj[3];
#pragma unroll
        for (int n = 0; n < 3; ++n)
            rj[n] = *(const f32x4*)(RJl + (c * 96 + jl[n]) * 16);
        f32x4 qi[3][4];
#pragma unroll
        for (int m = 0; m < 3; ++m)
#pragma unroll
            for (int r = 0; r < 4; ++r)
                qi[m][r] = *(const f32x4*)(QIl + (c * 96 + il[m] + r) * 16);
        f32x4 w2v = *(const f32x4*)(W2 + 32 + c * 4);   // 32+c*4 = 64+(c-8)*4
#pragma unroll
        for (int m = 0; m < 3; ++m)
#pragma unroll
            for (int n = 0; n < 3; ++n)
#pragma unroll
                for (int r = 0; r < 4; ++r)
#pragma unroll
                    for (int e = 0; e < 4; ++e)
                        mm[m][n][r] = fmaf(fmaxf(qi[m][r][e] + rj[n][e], 0.f),
                                           w2v[e], mm[m][n][r]);
    }

    // ---- final: out = A*(m1+bb1) + acc*(m2+bb2) + diag(c0)
#pragma unroll
    for (int m = 0; m < 3; ++m)
#pragma unroll
        for (int n = 0; n < 3; ++n)
#pragma unroll
            for (int r = 0; r < 4; ++r) {
                float v = av[m][n][r] + acc[m][n][r] * (mm[m][n][r] + bb2);
                int gi = i0 + il[m] + r;
                int gj = j0 + jl[n];
                if (gi == gj) v += c0;
                out[(size_t)gi * NN + gj] = v;
            }
}

// ---------------------------------------------------------------------------
extern "C" void kernel_launch(void* const* d_in, const int* in_sizes, int n_in,
                              void* d_out, int out_size, void* d_ws, size_t ws_size,
                              hipStream_t stream) {
    const float* A  = (const float*)d_in[0];   // [NN,NN] A_norm (symmetric)
    const float* P  = (const float*)d_in[1];   // [NN,32]
    const float* W1 = (const float*)d_in[2];   // [3,32,32]
    const float* b1 = (const float*)d_in[3];   // [3,32]
    const float* W2 = (const float*)d_in[4];   // [3,32,1]
    const float* b2 = (const float*)d_in[5];   // [3,1]
    float* out = (float*)d_out;

    unsigned short* Ahh = (unsigned short*)d_ws;                 // NN*NN bf16
    unsigned short* All = Ahh + (size_t)NN * NN;                 // NN*NN bf16
    float* QIp = (float*)(All + (size_t)NN * NN);                // NN*64 f32
    float* RJn = QIp + (size_t)NN * 64;                          // NN*64 f32

    gud_split<<<dim3(NN * NN / 1024), 256, 0, stream>>>(A, Ahh, All);
    gud_prep<<<dim3(NN * 64 / 256), 256, 0, stream>>>(P, W1, b1, QIp, RJn);
    gud_gemm<<<dim3(NN / TG, NN / TG), 256, 0, stream>>>(Ahh, All, A, QIp, RJn,
                                                         b1, W2, b2, out);
}